// Round 14
// baseline (19.829 us; speedup 1.0000x reference)
//
#include <hip/hip_runtime.h>
#include <math.h>

#define BB 64
#define LL 512
#define DD 768
#define HH 768
#define KK 128

static __device__ __forceinline__ float4 fmax4(float4 a, float4 b) {
    float4 r;
    r.x = fmaxf(a.x, b.x); r.y = fmaxf(a.y, b.y);
    r.z = fmaxf(a.z, b.z); r.w = fmaxf(a.w, b.w);
    return r;
}

// ws layout (floats): feat[64*768] | h[64*768]
#define FEAT_OFF 0
#define H_OFF    (BB * DD)

// ---------------------------------------------------------------------------
// Kernel A: compaction scan + span-max gather -> feat (ws).
// grid: (B, 3 parts) = 192 blocks ; block: 512 (8 waves).
// ---------------------------------------------------------------------------
__global__ __launch_bounds__(512) void halton_feat_kernel(
    const float* __restrict__ enc,        // (B, L, D)
    const int*   __restrict__ valid_mask, // (B, L)
    const int*   __restrict__ pos_span,   // (B, 2)
    float*       __restrict__ feat)       // (B, D)
{
    __shared__ int    s_idx[40];
    __shared__ int    s_count;
    __shared__ float4 s_red[8][64];       // 8 KB

    const int b    = blockIdx.x;
    const int part = blockIdx.y;          // 0..2
    const int tid  = threadIdx.x;

    // hoist span loads off the post-sync critical path
    const int lo = pos_span[b * 2 + 0];
    const int hi = pos_span[b * 2 + 1];   // <= 39 by construction

    if (tid < 64) {                       // wave 0: prefetched ballot scan
        int v[8];
        #pragma unroll
        for (int c = 0; c < 8; ++c)       // 8 independent loads, one latency
            v[c] = valid_mask[b * LL + c * 64 + tid];
        int count = 0;
        #pragma unroll
        for (int c = 0; c < 8; ++c) {
            unsigned long long mk = __ballot(v[c] == 1);
            if (v[c] == 1) {
                int rank = count + __popcll(mk & ((1ull << tid) - 1ull));
                if (rank < 40) s_idx[rank] = c * 64 + tid;
            }
            count += __popcll(mk);
        }
        if (tid == 0) s_count = count;
    }
    __syncthreads();

    const int count = s_count;
    const int pend  = min(hi, count - 1);

    const int c4   = tid & 63;            // float4 column within this part
    const int g    = tid >> 6;            // row-group 0..7
    const int fcol = part * 64 + c4;

    float4 m = make_float4(-INFINITY, -INFINITY, -INFINITY, -INFINITY);
    for (int p = lo + g; p <= pend; p += 8) {
        m = fmax4(m, ((const float4*)&enc[((long)b * LL + s_idx[p]) * DD])[fcol]);
    }
    if (hi >= count) m = fmax4(m, make_float4(0.f, 0.f, 0.f, 0.f));
    s_red[g][c4] = m;
    __syncthreads();

    if (g == 0) {
        float4 r = s_red[0][c4];
        #pragma unroll
        for (int q = 1; q < 8; ++q) r = fmax4(r, s_red[q][c4]);
        ((float4*)&feat[(long)b * DD])[fcol] = r;
    }
}

// ---------------------------------------------------------------------------
// Kernel B: h = relu(feat @ W1 + b1).
// grid: (12 j-tiles of 64, 16 b-tiles of 4) = 192 blocks ; block: 1024 (16 wv)
// wave wu = k-slice of 48; thread = 1 col x 4 batches.
// feat addresses are wave-uniform (readfirstlane-forced) -> scalar s_load
// path: zero VALU/LDS issue cost, replaces 768 ds_read_b128 broadcasts/CU.
// W1 vector-loaded once per block (coalesced). One barrier total.
// ---------------------------------------------------------------------------
__global__ __launch_bounds__(1024) void halton_gemm1_kernel(
    const float* __restrict__ feat,  // (B, D) in ws
    const float* __restrict__ W1,    // (D, H)
    const float* __restrict__ b1,    // (H)
    float*       __restrict__ h)     // (B, H) in ws
{
    __shared__ float s_part[16][4][64];  // [kslice][batch][col] 16 KB

    const int tid   = threadIdx.x;
    const int jbase = blockIdx.x * 64;
    const int bbase = blockIdx.y * 4;
    const int lane  = tid & 63;
    const int wu    = __builtin_amdgcn_readfirstlane(tid >> 6); // wave 0..15
    const int j     = jbase + lane;

    const float rb1 = b1[j];             // entry prefetch (combine uses it)

    // uniform per-batch feat row bases (feat is const __restrict -> s_load)
    const float* f0 = &feat[(long)(bbase + 0) * DD + wu * 48];
    const float* f1 = &feat[(long)(bbase + 1) * DD + wu * 48];
    const float* f2 = &feat[(long)(bbase + 2) * DD + wu * 48];
    const float* f3 = &feat[(long)(bbase + 3) * DD + wu * 48];
    const float* wp = &W1[(long)(wu * 48) * HH + j];

    float a0 = 0.f, a1 = 0.f, a2 = 0.f, a3 = 0.f;
    #pragma unroll 4
    for (int k4 = 0; k4 < 12; ++k4) {
        const float4 fv0 = *(const float4*)(f0 + k4 * 4);  // scalar loads
        const float4 fv1 = *(const float4*)(f1 + k4 * 4);
        const float4 fv2 = *(const float4*)(f2 + k4 * 4);
        const float4 fv3 = *(const float4*)(f3 + k4 * 4);
        const float w0 = wp[(k4 * 4 + 0) * HH];            // coalesced vector
        const float w1 = wp[(k4 * 4 + 1) * HH];
        const float w2 = wp[(k4 * 4 + 2) * HH];
        const float w3 = wp[(k4 * 4 + 3) * HH];
        a0 += fv0.x * w0 + fv0.y * w1 + fv0.z * w2 + fv0.w * w3;
        a1 += fv1.x * w0 + fv1.y * w1 + fv1.z * w2 + fv1.w * w3;
        a2 += fv2.x * w0 + fv2.y * w1 + fv2.z * w2 + fv2.w * w3;
        a3 += fv3.x * w0 + fv3.y * w1 + fv3.z * w2 + fv3.w * w3;
    }
    s_part[wu][0][lane] = a0;
    s_part[wu][1][lane] = a1;
    s_part[wu][2][lane] = a2;
    s_part[wu][3][lane] = a3;
    __syncthreads();

    // combine: threads 0..255 -> (batch = t>>6, col = t&63), sum 16 k-slices
    if (tid < 256) {
        const int bl  = tid >> 6;
        const int col = tid & 63;
        float r = rb1;                    // == b1[jbase+col] for these threads
        #pragma unroll
        for (int q = 0; q < 16; ++q) r += s_part[q][bl][col];
        h[(long)(bbase + bl) * HH + jbase + col] = fmaxf(r, 0.f);
    }
}

// ---------------------------------------------------------------------------
// Kernel C: out = h @ W2 + b2.
// grid: (2 col-tiles of 64, 64 batches) = 128 blocks ; block: 384 (6 waves).
// wave wu = k-slice of 128; h read via uniform scalar loads; W2 once/block.
// ---------------------------------------------------------------------------
__global__ __launch_bounds__(384) void halton_gemm2_kernel(
    const float* __restrict__ h,     // (B, H) in ws
    const float* __restrict__ W2,    // (H, K)
    const float* __restrict__ b2,    // (K)
    float*       __restrict__ out)   // (B, K)
{
    __shared__ float s_part[6][64];  // 1.5 KB

    const int tid  = threadIdx.x;
    const int b    = blockIdx.y;
    const int lane = tid & 63;
    const int wu   = __builtin_amdgcn_readfirstlane(tid >> 6);  // 0..5
    const int col  = blockIdx.x * 64 + lane;

    const float rb2 = b2[col];       // entry prefetch
    const float* hb = &h[(long)b * HH + wu * 128];   // uniform -> s_load
    const float* wp = &W2[(long)(wu * 128) * KK + col];

    float a0 = 0.f, a1 = 0.f, a2 = 0.f, a3 = 0.f;
    #pragma unroll 4
    for (int i4 = 0; i4 < 32; ++i4) {
        const float4 hv = *(const float4*)(hb + i4 * 4);  // scalar load
        a0 += hv.x * wp[(i4 * 4 + 0) * KK];               // coalesced vector
        a1 += hv.y * wp[(i4 * 4 + 1) * KK];
        a2 += hv.z * wp[(i4 * 4 + 2) * KK];
        a3 += hv.w * wp[(i4 * 4 + 3) * KK];
    }
    s_part[wu][lane] = (a0 + a1) + (a2 + a3);
    __syncthreads();

    if (tid < 64) {
        float r = rb2;                    // == b2[col] for these threads
        #pragma unroll
        for (int q = 0; q < 6; ++q) r += s_part[q][tid];
        out[b * KK + blockIdx.x * 64 + tid] = r;
    }
}

extern "C" void kernel_launch(void* const* d_in, const int* in_sizes, int n_in,
                              void* d_out, int out_size, void* d_ws, size_t ws_size,
                              hipStream_t stream) {
    const float* enc        = (const float*)d_in[0];
    const float* W1         = (const float*)d_in[1];
    const float* b1         = (const float*)d_in[2];
    const float* W2         = (const float*)d_in[3];
    const float* b2         = (const float*)d_in[4];
    const int*   valid_mask = (const int*)d_in[5];
    const int*   pos_span   = (const int*)d_in[6];
    // d_in[7] = mask_span: dead code (mask_feat unused by the reference output)
    float* out  = (float*)d_out;
    float* feat = (float*)d_ws + FEAT_OFF;
    float* h    = (float*)d_ws + H_OFF;

    halton_feat_kernel<<<dim3(BB, 3), 512, 0, stream>>>(enc, valid_mask, pos_span, feat);
    halton_gemm1_kernel<<<dim3(12, 16), 1024, 0, stream>>>(feat, W1, b1, h);
    halton_gemm2_kernel<<<dim3(2, BB), 384, 0, stream>>>(h, W2, b2, out);
}

// Round 15
// 18.829 us; speedup vs baseline: 1.0531x; 1.0531x over previous
//
#include <hip/hip_runtime.h>
#include <math.h>

#define BB 64
#define LL 512
#define DD 768
#define HH 768
#define KK 128

static __device__ __forceinline__ float4 fmax4(float4 a, float4 b) {
    float4 r;
    r.x = fmaxf(a.x, b.x); r.y = fmaxf(a.y, b.y);
    r.z = fmaxf(a.z, b.z); r.w = fmaxf(a.w, b.w);
    return r;
}

// ---------------------------------------------------------------------------
// K1: fused {ballot-scan + 4-way-row-parallel span-max gather} + GEMM1.
// grid: (12 j-tiles of 64, 16 b-tiles of 4) = 192 blocks ; block: 1024 (16 wv)
//  entry : prefetch b1, pos_span, first W1 group (independent of barriers).
//  Phase 0: waves 0..3 scan valid_mask (one batch each).          [barrier]
//  Phase 1: wave = (batch w&3, row-group w>>2) span-max gather.   [barrier]
//  Phase 1.5 (no barrier): wave w's lanes 0..47 fmax-reduce ONLY its own
//           k-slice of feat (cols 48w..48w+48) -> s_feat.
//  Phase 2: wave = k-slice of 48; thread = 1 col x 4 batches; W1 once/block.
//                                                                 [barrier]
//  combine: threads 0..255 sum 16 k-slice partials + b1 -> h.
// ---------------------------------------------------------------------------
__global__ __launch_bounds__(1024, 1) void halton_featmlp_kernel(
    const float* __restrict__ enc,        // (B, L, D)
    const float* __restrict__ W1,         // (D, H)
    const float* __restrict__ b1,         // (H)
    const int*   __restrict__ valid_mask, // (B, L)
    const int*   __restrict__ pos_span,   // (B, 2)
    float*       __restrict__ h)          // (B, H)
{
    __shared__ int    s_idx[4][40];
    __shared__ int    s_count[4];
    __shared__ float4 s_red[4][4][192];    // [g][bl][fc] 49 KB
    __shared__ float  s_feat[4][DD];       // 12 KB
    __shared__ float  s_part[16][4][64];   // [kslice][batch][col] 16 KB

    const int tid   = threadIdx.x;
    const int jbase = blockIdx.x * 64;
    const int bbase = blockIdx.y * 4;
    const int lane  = tid & 63;
    const int w     = tid >> 6;            // wave 0..15
    const int j     = jbase + lane;

    // ---- entry prefetches (independent of scan/gather) ---------------------
    const float rb1 = b1[jbase + lane];            // used in combine
    const int   kp  = w * 48;                      // this wave's first k
    float w0p = W1[(kp + 0) * HH + j];             // first GEMM iter's W1
    float w1p = W1[(kp + 1) * HH + j];
    float w2p = W1[(kp + 2) * HH + j];
    float w3p = W1[(kp + 3) * HH + j];
    const int bl_g = w & 3;                        // gather batch
    const int g_g  = w >> 2;                       // gather row-group
    const int bgat = bbase + bl_g;
    const int lo   = pos_span[bgat * 2 + 0];
    const int hi   = pos_span[bgat * 2 + 1];       // <= 39 by construction

    // ---- Phase 0: prefetched ballot scan, waves 0..3 -----------------------
    if (w < 4) {
        const int b = bbase + w;
        int v[8];
        #pragma unroll
        for (int c = 0; c < 8; ++c)        // 8 independent loads, one latency
            v[c] = valid_mask[b * LL + c * 64 + lane];
        int count = 0;
        #pragma unroll
        for (int c = 0; c < 8; ++c) {
            unsigned long long mk = __ballot(v[c] == 1);
            if (v[c] == 1) {
                int rank = count + __popcll(mk & ((1ull << lane) - 1ull));
                if (rank < 40) s_idx[w][rank] = c * 64 + lane;
            }
            count += __popcll(mk);
        }
        if (lane == 0) s_count[w] = count;
    }
    __syncthreads();

    // ---- Phase 1: span-max gather, wave = (batch, row-group) ---------------
    {
        const int count = s_count[bl_g];
        const int pend  = min(hi, count - 1);

        const float4 ninf = make_float4(-INFINITY, -INFINITY, -INFINITY, -INFINITY);
        float4 m0 = ninf, m1 = ninf, m2 = ninf;   // row p
        float4 n0 = ninf, n1 = ninf, n2 = ninf;   // row p+4
        for (int p = lo + g_g; p <= pend; p += 8) {
            const float4* r4 = (const float4*)&enc[((long)bgat * LL + s_idx[bl_g][p]) * DD];
            m0 = fmax4(m0, r4[lane]);
            m1 = fmax4(m1, r4[lane + 64]);
            m2 = fmax4(m2, r4[lane + 128]);
            if (p + 4 <= pend) {
                const float4* q4 = (const float4*)&enc[((long)bgat * LL + s_idx[bl_g][p + 4]) * DD];
                n0 = fmax4(n0, q4[lane]);
                n1 = fmax4(n1, q4[lane + 64]);
                n2 = fmax4(n2, q4[lane + 128]);
            }
        }
        m0 = fmax4(m0, n0); m1 = fmax4(m1, n1); m2 = fmax4(m2, n2);
        if (hi >= count) {                 // zero row(s) inside span
            const float4 z = make_float4(0.f, 0.f, 0.f, 0.f);
            m0 = fmax4(m0, z); m1 = fmax4(m1, z); m2 = fmax4(m2, z);
        }
        s_red[g_g][bl_g][lane]       = m0;
        s_red[g_g][bl_g][lane + 64]  = m1;
        s_red[g_g][bl_g][lane + 128] = m2;
    }
    __syncthreads();

    // ---- Phase 1.5 (no barrier): per-wave tree over ONLY this wave's slice -
    // wave w consumes feat f4-cols [12w, 12w+12) x 4 batches = 48 values.
    if (lane < 48) {
        const int bl = lane / 12;
        const int kf = w * 12 + lane % 12;
        float4 r = fmax4(fmax4(s_red[0][bl][kf], s_red[1][bl][kf]),
                         fmax4(s_red[2][bl][kf], s_red[3][bl][kf]));
        ((float4*)&s_feat[bl][0])[kf] = r;
    }
    // wave-local LDS write->read: ordered by lgkmcnt, no block barrier needed

    // ---- Phase 2: GEMM1, wave = k-slice of 48, thread = 1 col x 4 batches --
    {
        const float4* f40 = (const float4*)&s_feat[0][0];
        const float4* f41 = (const float4*)&s_feat[1][0];
        const float4* f42 = (const float4*)&s_feat[2][0];
        const float4* f43 = (const float4*)&s_feat[3][0];

        float a0, a1, a2, a3;
        {   // k4 = 0: use entry-prefetched W1 values
            const int kf = w * 12;
            const float4 fv0 = f40[kf], fv1 = f41[kf], fv2 = f42[kf], fv3 = f43[kf];
            a0 = fv0.x * w0p + fv0.y * w1p + fv0.z * w2p + fv0.w * w3p;
            a1 = fv1.x * w0p + fv1.y * w1p + fv1.z * w2p + fv1.w * w3p;
            a2 = fv2.x * w0p + fv2.y * w1p + fv2.z * w2p + fv2.w * w3p;
            a3 = fv3.x * w0p + fv3.y * w1p + fv3.z * w2p + fv3.w * w3p;
        }
        #pragma unroll 4
        for (int k4 = 1; k4 < 12; ++k4) {
            const int kf = w * 12 + k4;
            const int k  = kf * 4;
            const float4 fv0 = f40[kf];    // LDS b128 broadcasts
            const float4 fv1 = f41[kf];
            const float4 fv2 = f42[kf];
            const float4 fv3 = f43[kf];
            const float w0 = W1[(k + 0) * HH + j];   // coalesced, once/block
            const float w1 = W1[(k + 1) * HH + j];
            const float w2 = W1[(k + 2) * HH + j];
            const float w3 = W1[(k + 3) * HH + j];
            a0 += fv0.x * w0 + fv0.y * w1 + fv0.z * w2 + fv0.w * w3;
            a1 += fv1.x * w0 + fv1.y * w1 + fv1.z * w2 + fv1.w * w3;
            a2 += fv2.x * w0 + fv2.y * w1 + fv2.z * w2 + fv2.w * w3;
            a3 += fv3.x * w0 + fv3.y * w1 + fv3.z * w2 + fv3.w * w3;
        }
        s_part[w][0][lane] = a0;
        s_part[w][1][lane] = a1;
        s_part[w][2][lane] = a2;
        s_part[w][3][lane] = a3;
    }
    __syncthreads();

    // ---- combine: threads 0..255 -> (batch = t>>6, col = t&63) -------------
    if (tid < 256) {
        const int bl  = tid >> 6;
        const int col = tid & 63;
        float r = rb1;                     // b1[jbase+col], prefetched
        #pragma unroll
        for (int q = 0; q < 16; ++q) r += s_part[q][bl][col];
        h[(long)(bbase + bl) * HH + jbase + col] = fmaxf(r, 0.f);
    }
}

// ---------------------------------------------------------------------------
// K2: out = h @ W2 + b2. No LDS staging of h: half-wave-uniform global loads
// broadcast through L1 (h row is L2-resident from K1). One barrier total.
// grid: (4 col-tiles of 32, 64 batches) = 256 blocks ; block: 384 (6 waves).
// ---------------------------------------------------------------------------
__global__ __launch_bounds__(384) void halton_gemm2_kernel(
    const float* __restrict__ h,     // (B, H)
    const float* __restrict__ W2,    // (H, K)
    const float* __restrict__ b2,    // (K)
    float*       __restrict__ out)   // (B, K)
{
    __shared__ float s_part[12][32]; // 1.5 KB

    const int tid = threadIdx.x;
    const int b   = blockIdx.y;
    const int col = blockIdx.x * 32 + (tid & 31);
    const int seg = tid >> 5;        // k-slice 0..11

    const float rb2 = b2[col];       // entry prefetch
    const float4* h4 = (const float4*)&h[(long)b * HH + seg * 64];

    float a0 = 0.f, a1 = 0.f, a2 = 0.f, a3 = 0.f;
    #pragma unroll 4
    for (int i4 = 0; i4 < 16; ++i4) {
        const float4 hv = h4[i4];    // uniform per half-wave -> L1 broadcast
        const int k = seg * 64 + i4 * 4;
        a0 += hv.x * W2[(k + 0) * KK + col];   // 128B/half-wave, once/block
        a1 += hv.y * W2[(k + 1) * KK + col];
        a2 += hv.z * W2[(k + 2) * KK + col];
        a3 += hv.w * W2[(k + 3) * KK + col];
    }
    s_part[seg][tid & 31] = (a0 + a1) + (a2 + a3);
    __syncthreads();

    if (tid < 32) {
        float r = rb2;
        #pragma unroll
        for (int q = 0; q < 12; ++q) r += s_part[q][tid];
        out[b * KK + col] = r;
    }
}

extern "C" void kernel_launch(void* const* d_in, const int* in_sizes, int n_in,
                              void* d_out, int out_size, void* d_ws, size_t ws_size,
                              hipStream_t stream) {
    const float* enc        = (const float*)d_in[0];
    const float* W1         = (const float*)d_in[1];
    const float* b1         = (const float*)d_in[2];
    const float* W2         = (const float*)d_in[3];
    const float* b2         = (const float*)d_in[4];
    const int*   valid_mask = (const int*)d_in[5];
    const int*   pos_span   = (const int*)d_in[6];
    // d_in[7] = mask_span: dead code (mask_feat unused by the reference output)
    float* out = (float*)d_out;
    float* h   = (float*)d_ws;       // 64*768 floats

    halton_featmlp_kernel<<<dim3(12, 16), 1024, 0, stream>>>(enc, W1, b1,
                                                             valid_mask, pos_span, h);
    halton_gemm2_kernel<<<dim3(4, BB), 384, 0, stream>>>(h, W2, b2, out);
}